// Round 6
// baseline (422.941 us; speedup 1.0000x reference)
//
#include <hip/hip_runtime.h>
#include <math.h>

typedef float2 c2;

#define S_IDX(i) ((i) ^ (((i) >> 5) & 15))
#define SLAB_STRIDE 1025

__device__ __forceinline__ c2 cmul(c2 a, c2 b){
  return make_float2(a.x*b.x - a.y*b.y, a.x*b.y + a.y*b.x);
}

__constant__ float c_foinv[5] = {3.0f, 6.3f, 13.23f, 27.783f, 58.3443f};
__constant__ float c_lnfo[5]  = {1.0986123f, 1.8405496f, 2.5824700f, 3.3244106f, 4.0663219f};
__constant__ float c_angl[6]  = {0.0f, 0.5235988f, 1.0471976f, 1.5707963f, 2.0943951f, 2.6179939f};
__constant__ float c_cosA[6] = {1.0f, 0.8660254038f, 0.5f, 6.123233996e-17f, -0.5f, -0.8660254038f};
__constant__ float c_sinA[6] = {0.0f, 0.5f, 0.8660254038f, 1.0f, 0.8660254038f, 0.5f};

template<int SIGN>
__device__ __forceinline__ void make_tw(int t, c2* w){
#pragma unroll
  for (int k = 0; k < 5; ++k){
    const int s = 1 << (2*k);
    const float ang = (float)SIGN * 0.00613592315154256f * (float)(t & ~(s-1));
    sincosf(ang, &w[k].y, &w[k].x);
  }
}

// Radix-4 Stockham, N=1024, 256 threads. Data starts in bufA, ends in bufB.
template<int SIGN>
__device__ __forceinline__ void fft1024(c2* bufA, c2* bufB, int t, const c2* w){
  c2* cur = bufA; c2* oth = bufB;
#pragma unroll
  for (int k = 0; k < 5; ++k){
    const int s = 1 << (2*k);
    const int q = t & (s - 1);
    c2 a = cur[S_IDX(t)];
    c2 b = cur[S_IDX(t + 256)];
    c2 c = cur[S_IDX(t + 512)];
    c2 d = cur[S_IDX(t + 768)];
    c2 w1 = w[k];
    c2 w2 = cmul(w1, w1);
    c2 w3 = cmul(w2, w1);
    c2 apc = make_float2(a.x + c.x, a.y + c.y);
    c2 amc = make_float2(a.x - c.x, a.y - c.y);
    c2 bpd = make_float2(b.x + d.x, b.y + d.y);
    c2 bmd = make_float2(b.x - d.x, b.y - d.y);
    c2 y0 = make_float2(apc.x + bpd.x, apc.y + bpd.y);
    c2 e2 = make_float2(apc.x - bpd.x, apc.y - bpd.y);
    const float S4 = (float)SIGN;
    c2 u1 = make_float2(amc.x - S4*bmd.y, amc.y + S4*bmd.x);
    c2 u3 = make_float2(amc.x + S4*bmd.y, amc.y - S4*bmd.x);
    c2 y1 = cmul(u1, w1);
    c2 y2 = cmul(e2, w2);
    c2 y3 = cmul(u3, w3);
    const int bw = 4*t - 3*q;
    oth[S_IDX(bw)]       = y0;
    oth[S_IDX(bw + s)]   = y1;
    oth[S_IDX(bw + 2*s)] = y2;
    oth[S_IDX(bw + 3*s)] = y3;
    c2* tmp = cur; cur = oth; oth = tmp;
    __syncthreads();
  }
}

// Analytic filter at [r=ky (row), c=kx (col)]; yy precomputed from row.
__device__ __forceinline__ float filt_eval(int c, int r, float yy,
                                           float cosA, float sinA, float foinv){
  const float xx = (float)(c < 512 ? c : c - 1024) * (1.0f/1024.0f);
  const bool isdc = (c == 0) && (r == 0);
  const float radius = isdc ? 1.0f : sqrtf(xx*xx + yy*yy);
  const float tt = radius * (1.0f/0.45f);
  const float t2 = tt*tt, t4 = t2*t2, t8 = t4*t4, t16 = t8*t8;
  const float lp = 1.0f / (1.0f + t16*t8*t4*t2);
  const float lnr = logf(radius * foinv);
  const float lg = expf(-lnr*lnr * 1.3989572f);   // 1/(2*ln(0.55)^2)
  const float ir = 1.0f / radius;
  const float st = -yy * ir, ct = xx * ir;
  const float dsv = st*cosA - ct*sinA;
  const float dcv = ct*cosA + st*sinA;
  const float dth = fminf(fabsf(atan2f(dsv, dcv)) * 3.0f, 3.14159274f);
  const float spr = 0.5f * (cosf(dth) + 1.0f);
  const float f = lg * lp * spr;
  return isdc ? 0.0f : f;
}

// Tables in [ky (row)][kx (col)] layout: lnr = ln(radius), theta = atan2(-yy, xx).
__global__ __launch_bounds__(256) void k_filt_tab(float* __restrict__ lnrT, float* __restrict__ thetaT){
  const int r = blockIdx.x;
  const int t = threadIdx.x;
  const float yy = (float)(r < 512 ? r : r - 1024) * (1.0f/1024.0f);
#pragma unroll
  for (int j = 0; j < 4; ++j){
    const int c = t + 256*j;
    const float xx = (float)(c < 512 ? c : c - 1024) * (1.0f/1024.0f);
    const float radius = sqrtf(xx*xx + yy*yy);
    float lnr = logf(radius);
    if (r == 0 && c == 0) lnr = __int_as_float(0x7F800000);  // +inf -> filter 0 at DC
    lnrT[r*1024 + c] = lnr;
    thetaT[r*1024 + c] = atan2f(-yy, xx);
  }
}

// Row FFT of the real image: out[y][kx].
__global__ __launch_bounds__(256) void k_fft_fwd_real(const float* __restrict__ in, c2* __restrict__ out){
  const int t = threadIdx.x;
  __shared__ c2 bufA[1024];
  __shared__ c2 bufB[1024];
  c2 w[5]; make_tw<-1>(t, w);
  for (int rr = 0; rr < 4; ++rr){
    const int row = blockIdx.x * 4 + rr;
    const float* src = in + (size_t)row * 1024;
    c2* dst = out + (size_t)row * 1024;
#pragma unroll
    for (int j = 0; j < 4; ++j){
      const int q = t + 256*j;
      bufA[S_IDX(q)] = make_float2(src[q], 0.0f);
    }
    __syncthreads();
    fft1024<-1>(bufA, bufB, t, w);
#pragma unroll
    for (int j = 0; j < 4; ++j){ const int q = t + 256*j; dst[q] = bufB[S_IDX(q)]; }
    __syncthreads();
  }
}

// Fused column FFT: block owns an 8-column slab, FFTs down the columns in LDS,
// writes results back into the SAME columns (block-local in-place, no transpose).
template<int SIGN>
__global__ __launch_bounds__(256) void k_fft_col_slab(c2* __restrict__ Z){
  __shared__ c2 slab[8 * SLAB_STRIDE];   // 8 cols, padded stride (bank spread)
  __shared__ c2 bufB[1024];
  c2* base = Z + (size_t)blockIdx.y * 1048576;
  const int t = threadIdx.x;
  const int col0 = blockIdx.x * 8;
  const int cl = t & 7;        // column within slab
  const int rw = t >> 3;       // row within 32-row chunk
  c2 w[5]; make_tw<SIGN>(t, w);
  for (int ch = 0; ch < 32; ++ch){
    const int row = ch * 32 + rw;
    slab[cl * SLAB_STRIDE + S_IDX(row)] = base[(size_t)row * 1024 + col0 + cl];
  }
  __syncthreads();
  for (int c = 0; c < 8; ++c){
    c2* colp = slab + c * SLAB_STRIDE;
#pragma unroll
    for (int j = 0; j < 4; ++j) bufB[t + 256*j] = colp[t + 256*j];
    __syncthreads();
    fft1024<SIGN>(bufB, colp, t, w);   // ends in colp (5 stages), trailing sync
  }
  for (int ch = 0; ch < 32; ++ch){
    const int row = ch * 32 + rw;
    base[(size_t)row * 1024 + col0 + cl] = slab[cl * SLAB_STRIDE + S_IDX(row)];
  }
}

// Table-based: row r = ky of F; multiply filt[ky][kx], IFFT over kx -> Z[ky][x].
__global__ __launch_bounds__(256) void k_fft_inv_filter_t(const c2* __restrict__ F, c2* __restrict__ Z,
                                                          const float* __restrict__ lnrT,
                                                          const float* __restrict__ thetaT){
  const int t = threadIdx.x;
  const int gslot = blockIdx.y;
  const int orient = gslot / 5;
  const int scale = gslot - orient*5;
  const float lnfo = c_lnfo[scale];
  const float angl = c_angl[orient];
  __shared__ c2 bufA[1024];
  __shared__ c2 bufB[1024];
  c2 w[5]; make_tw<1>(t, w);
  for (int rr = 0; rr < 4; ++rr){
    const int row = blockIdx.x * 4 + rr;
    const c2* src = F + (size_t)row * 1024;
    const float* lnrR = lnrT + (size_t)row * 1024;
    const float* thR  = thetaT + (size_t)row * 1024;
    c2* dst = Z + (size_t)gslot * 1048576 + (size_t)row * 1024;
#pragma unroll
    for (int j = 0; j < 4; ++j){
      const int q = t + 256*j;
      const c2 v = src[q];
      const float lnr = lnrR[q];
      const float th  = thR[q];
      const float u = lnr + lnfo;
      const float lg = __expf(-u*u * 1.3989572f);
      const float lp = 1.0f / (1.0f + __expf(fmaf(30.0f, lnr, 23.955231f)));
      float d = th - angl;
      if (d <= -3.14159274f) d += 6.28318548f;
      const float dth = fminf(fabsf(d) * 3.0f, 3.14159274f);
      const float spr = 0.5f * (__cosf(dth) + 1.0f);
      const float f = lg * lp * spr;
      bufA[S_IDX(q)] = make_float2(v.x*f, v.y*f);
    }
    __syncthreads();
    fft1024<1>(bufA, bufB, t, w);
#pragma unroll
    for (int j = 0; j < 4; ++j){ const int q = t + 256*j; dst[q] = bufB[S_IDX(q)]; }
    __syncthreads();
  }
}

// Analytic variant (fallback path). slot0 + blockIdx.y selects (orient,scale).
__global__ __launch_bounds__(256) void k_fft_inv_filter_b(const c2* __restrict__ F, c2* __restrict__ Z,
                                                          int slot0){
  const int t = threadIdx.x;
  const int gslot = slot0 + blockIdx.y;
  const int orient = gslot / 5;
  const int scale = gslot - orient*5;
  const float foinv = c_foinv[scale];
  const float cosA = c_cosA[orient], sinA = c_sinA[orient];
  __shared__ c2 bufA[1024];
  __shared__ c2 bufB[1024];
  c2 w[5]; make_tw<1>(t, w);
  for (int rr = 0; rr < 4; ++rr){
    const int row = blockIdx.x * 4 + rr;     // ky
    const c2* src = F + (size_t)row * 1024;
    c2* dst = Z + (size_t)blockIdx.y * 1048576 + (size_t)row * 1024;
    const float yy = (float)(row < 512 ? row : row - 1024) * (1.0f/1024.0f);
#pragma unroll
    for (int j = 0; j < 4; ++j){
      const int q = t + 256*j;
      const c2 v = src[q];
      const float f = filt_eval(q, row, yy, cosA, sinA, foinv);
      bufA[S_IDX(q)] = make_float2(v.x*f, v.y*f);
    }
    __syncthreads();
    fft1024<1>(bufA, bufB, t, w);
#pragma unroll
    for (int j = 0; j < 4; ++j){ const int q = t + 256*j; dst[q] = bufB[S_IDX(q)]; }
    __syncthreads();
  }
}

// ---------------- exact median via 3-level radix select (12/12/8 bits) ----------

__device__ __forceinline__ unsigned amp_bits(const c2 v){
  return __float_as_uint(sqrtf(v.x*v.x + v.y*v.y));
}

__global__ __launch_bounds__(256) void k_med_p1b(const c2* __restrict__ Zb, size_t oStride,
                                                 unsigned* __restrict__ g1, int oBase){
  __shared__ unsigned h[4][4096];
  const int t = threadIdx.x;
  const int wv = t >> 6;
  const c2* z0 = Zb + (size_t)blockIdx.y * oStride;
  unsigned* gg = g1 + (size_t)(oBase + blockIdx.y) * 4096;
  for (int j = t; j < 4*4096; j += 256) ((unsigned*)h)[j] = 0;
  __syncthreads();
  const int base = blockIdx.x * 16384;
  for (int it = 0; it < 64; ++it){
    const unsigned bits = amp_bits(z0[base + it*256 + t]);
    atomicAdd(&h[wv][bits >> 20], 1u);
  }
  __syncthreads();
  for (int j = t; j < 4096; j += 256){
    const unsigned s = h[0][j] + h[1][j] + h[2][j] + h[3][j];
    if (s) atomicAdd(&gg[j], s);
  }
}

__global__ __launch_bounds__(256) void k_sel1b(const unsigned* __restrict__ g1,
                                               unsigned* __restrict__ sc1,
                                               unsigned* __restrict__ g2, int oBase){
  __shared__ unsigned partial[256];
  const int t = threadIdx.x;
  const int oo = oBase + blockIdx.x;
  const unsigned* gg = g1 + (size_t)oo * 4096;
  unsigned loc[16]; unsigned s = 0;
#pragma unroll
  for (int j = 0; j < 16; ++j){ loc[j] = gg[t*16 + j]; s += loc[j]; }
  partial[t] = s;
  __syncthreads();
  unsigned p = 0;
  for (int u = 0; u < t; ++u) p += partial[u];
  for (int which = 0; which < 2; ++which){
    const unsigned R = 524287u + (unsigned)which;
    if (R >= p && R - p < s){
      unsigned cum = p;
      for (int j = 0; j < 16; ++j){
        if (R - cum < loc[j]){ sc1[oo*4 + which*2] = (unsigned)(t*16 + j); sc1[oo*4 + which*2+1] = R - cum; break; }
        cum += loc[j];
      }
    }
  }
  for (int j = t; j < 8192; j += 256) g2[(size_t)oo*8192 + j] = 0;
}

__global__ __launch_bounds__(256) void k_med_p2b(const c2* __restrict__ Zb, size_t oStride,
                                                 const unsigned* __restrict__ sc1,
                                                 unsigned* __restrict__ g2, int oBase){
  __shared__ unsigned h[2][4096];
  const int t = threadIdx.x;
  const int oo = oBase + blockIdx.y;
  const c2* z0 = Zb + (size_t)blockIdx.y * oStride;
  unsigned* gg = g2 + (size_t)oo * 8192;
  for (int j = t; j < 8192; j += 256) ((unsigned*)h)[j] = 0;
  __syncthreads();
  const unsigned b0 = sc1[oo*4 + 0], b1 = sc1[oo*4 + 2];
  const int base = blockIdx.x * 16384;
  for (int it = 0; it < 64; ++it){
    const unsigned bits = amp_bits(z0[base + it*256 + t]);
    const unsigned top = bits >> 20;
    const unsigned mid = (bits >> 8) & 4095u;
    if (top == b0)      atomicAdd(&h[0][mid], 1u);
    else if (top == b1) atomicAdd(&h[1][mid], 1u);
  }
  __syncthreads();
  for (int j = t; j < 4096; j += 256){
    if (h[0][j]) atomicAdd(&gg[j], h[0][j]);
    if (h[1][j]) atomicAdd(&gg[4096 + j], h[1][j]);
  }
}

__global__ __launch_bounds__(256) void k_sel2b(const unsigned* __restrict__ g2,
                                               const unsigned* __restrict__ sc1,
                                               unsigned* __restrict__ sc2,
                                               unsigned* __restrict__ g3, int oBase){
  __shared__ unsigned partial[256];
  const int t = threadIdx.x;
  const int oo = oBase + blockIdx.x;
  const unsigned b0 = sc1[oo*4+0], lr0 = sc1[oo*4+1], b1 = sc1[oo*4+2], lr1 = sc1[oo*4+3];
  for (int which = 0; which < 2; ++which){
    const unsigned* hh = g2 + (size_t)oo*8192 + ((which == 1 && b1 != b0) ? 4096 : 0);
    const unsigned R = which ? lr1 : lr0;
    unsigned loc[16]; unsigned s = 0;
#pragma unroll
    for (int j = 0; j < 16; ++j){ loc[j] = hh[t*16 + j]; s += loc[j]; }
    partial[t] = s;
    __syncthreads();
    unsigned p = 0;
    for (int u = 0; u < t; ++u) p += partial[u];
    if (R >= p && R - p < s){
      unsigned cum = p;
      for (int j = 0; j < 16; ++j){
        if (R - cum < loc[j]){ sc2[oo*4 + which*2] = (unsigned)(t*16 + j); sc2[oo*4 + which*2+1] = R - cum; break; }
        cum += loc[j];
      }
    }
    __syncthreads();
  }
  for (int j = t; j < 512; j += 256) g3[(size_t)oo*512 + j] = 0;
}

__global__ __launch_bounds__(256) void k_med_p3b(const c2* __restrict__ Zb, size_t oStride,
                                                 const unsigned* __restrict__ sc1,
                                                 const unsigned* __restrict__ sc2,
                                                 unsigned* __restrict__ g3, int oBase){
  __shared__ unsigned h[2][256];
  const int t = threadIdx.x;
  const int oo = oBase + blockIdx.y;
  const c2* z0 = Zb + (size_t)blockIdx.y * oStride;
  unsigned* gg = g3 + (size_t)oo * 512;
  h[0][t] = 0; h[1][t] = 0;
  __syncthreads();
  const unsigned k0 = (sc1[oo*4+0] << 12) | sc2[oo*4+0];
  const unsigned k1 = (sc1[oo*4+2] << 12) | sc2[oo*4+2];
  const int base = blockIdx.x * 16384;
  for (int it = 0; it < 64; ++it){
    const unsigned bits = amp_bits(z0[base + it*256 + t]);
    const unsigned key = bits >> 8;
    if (key == k0)       atomicAdd(&h[0][bits & 255u], 1u);
    else if (key == k1)  atomicAdd(&h[1][bits & 255u], 1u);
  }
  __syncthreads();
  if (h[0][t]) atomicAdd(&gg[t], h[0][t]);
  if (h[1][t]) atomicAdd(&gg[256 + t], h[1][t]);
}

__global__ __launch_bounds__(256) void k_sel3b(const unsigned* __restrict__ g3,
                                               const unsigned* __restrict__ sc1,
                                               const unsigned* __restrict__ sc2,
                                               float* __restrict__ Tval, int oBase){
  __shared__ unsigned partial[256];
  __shared__ float vres[2];
  const int t = threadIdx.x;
  const int oo = oBase + blockIdx.x;
  const unsigned k0 = (sc1[oo*4+0] << 12) | sc2[oo*4+0];
  const unsigned k1 = (sc1[oo*4+2] << 12) | sc2[oo*4+2];
  for (int which = 0; which < 2; ++which){
    const unsigned* hh = g3 + (size_t)oo*512 + ((which == 1 && k1 != k0) ? 256 : 0);
    const unsigned R = which ? sc2[oo*4+3] : sc2[oo*4+1];
    partial[t] = hh[t];
    __syncthreads();
    unsigned p = 0;
    for (int u = 0; u < t; ++u) p += partial[u];
    if (R >= p && R - p < partial[t]){
      const unsigned key = which ? k1 : k0;
      vres[which] = __uint_as_float((key << 8) | (unsigned)t);
    }
    __syncthreads();
  }
  if (t == 0){
    const float med = 0.5f * (vres[0] + vres[1]);
    const float tau = med / 1.17741001f;              // sqrt(ln 4)
    const float totalTau = tau * 1.8623464f;          // (1-(1/2.1)^5)/(1-1/2.1)
    const float T = totalTau * 1.25331414f + 2.0f * totalTau * 0.65513638f;
    Tval[oo] = T;
  }
}

// ---------------- fused per-pixel: all 6 orientations + final M,m ----------------

__global__ __launch_bounds__(256) void k_pix_all(const c2* __restrict__ Z, const float* __restrict__ Tval,
                                                 float* __restrict__ out){
  const int i = blockIdx.x * 256 + threadIdx.x;
  float covx2 = 0.f, covy2 = 0.f, covxy = 0.f;
#pragma unroll
  for (int o = 0; o < 6; ++o){
    const float T = Tval[o];
    float E[5], O[5];
    float sumE = 0.f, sumO = 0.f, sumAn = 0.f, maxAn = 0.f;
#pragma unroll
    for (int s = 0; s < 5; ++s){
      const c2 z = Z[(size_t)(o*5 + s) * 1048576 + i];
      O[s] = z.x; E[s] = z.y;
      const float an = sqrtf(z.x*z.x + z.y*z.y);
      sumE += E[s]; sumO += O[s]; sumAn += an; maxAn = fmaxf(maxAn, an);
    }
    const float XE = sqrtf(sumE*sumE + sumO*sumO) + 1e-4f;
    const float ME = sumE / XE, MO = sumO / XE;
    float energy = 0.f;
#pragma unroll
    for (int s = 0; s < 5; ++s)
      energy += E[s]*ME + O[s]*MO - fabsf(E[s]*MO - O[s]*ME);
    energy = fmaxf(energy - T, 0.f);
    const float width = (sumAn / (maxAn + 1e-4f) - 1.0f) * 0.25f;
    const float weight = 1.0f / (1.0f + expf((0.5f - width) * 10.0f));
    const float PC = weight * energy / sumAn;
    const float cx = PC * c_cosA[o], cy = PC * c_sinA[o];
    covx2 += cx*cx; covy2 += cy*cy; covxy += cx*cy;
  }
  covx2 *= (1.0f/3.0f);
  covy2 *= (1.0f/3.0f);
  covxy *= (4.0f/6.0f);
  const float dnm = sqrtf(covxy*covxy + (covx2 - covy2)*(covx2 - covy2)) + 1e-4f;
  const float ss = covy2 + covx2;
  out[i] = (ss + dnm) / 2.0f;
  out[1048576 + i] = (ss - dnm) / 2.0f;
}

// ---------------- fallback per-orientation pixel kernels ----------------

__global__ __launch_bounds__(256) void k_pix(const c2* __restrict__ Z, const float* __restrict__ Tp,
                                             float cA, float sA,
                                             float* __restrict__ ax2, float* __restrict__ ay2,
                                             float* __restrict__ axy, int first){
  const int i = blockIdx.x * 256 + threadIdx.x;
  const float T = *Tp;
  float E[5], O[5];
  float sumE = 0.f, sumO = 0.f, sumAn = 0.f, maxAn = 0.f;
#pragma unroll
  for (int s = 0; s < 5; ++s){
    const c2 z = Z[(size_t)s * 1048576 + i];
    O[s] = z.x; E[s] = z.y;
    const float an = sqrtf(z.x*z.x + z.y*z.y);
    sumE += E[s]; sumO += O[s]; sumAn += an; maxAn = fmaxf(maxAn, an);
  }
  const float XE = sqrtf(sumE*sumE + sumO*sumO) + 1e-4f;
  const float ME = sumE / XE, MO = sumO / XE;
  float energy = 0.f;
#pragma unroll
  for (int s = 0; s < 5; ++s)
    energy += E[s]*ME + O[s]*MO - fabsf(E[s]*MO - O[s]*ME);
  energy = fmaxf(energy - T, 0.f);
  const float width = (sumAn / (maxAn + 1e-4f) - 1.0f) * 0.25f;
  const float weight = 1.0f / (1.0f + expf((0.5f - width) * 10.0f));
  const float PC = weight * energy / sumAn;
  const float cx = PC * cA, cy = PC * sA;
  if (first){ ax2[i] = cx*cx; ay2[i] = cy*cy; axy[i] = cx*cy; }
  else      { ax2[i] += cx*cx; ay2[i] += cy*cy; axy[i] += cx*cy; }
}

__global__ __launch_bounds__(256) void k_final(const float* __restrict__ ax2, const float* __restrict__ ay2,
                                               const float* __restrict__ axy, float* __restrict__ out){
  const int i = blockIdx.x * 256 + threadIdx.x;
  const float cx2 = ax2[i] / 3.0f;
  const float cy2 = ay2[i] / 3.0f;
  const float cxy = 4.0f * axy[i] / 6.0f;
  const float dnm = sqrtf(cxy*cxy + (cx2 - cy2)*(cx2 - cy2)) + 1e-4f;
  const float ss = cy2 + cx2;
  out[i] = (ss + dnm) / 2.0f;
  out[1048576 + i] = (ss - dnm) / 2.0f;
}

extern "C" void kernel_launch(void* const* d_in, const int* in_sizes, int n_in,
                              void* d_out, int out_size, void* d_ws, size_t ws_size,
                              hipStream_t stream){
  (void)in_sizes; (void)n_in; (void)out_size;
  const float* img = (const float*)d_in[0];
  float* out = (float*)d_out;
  char* w = (char*)d_ws;

  const dim3 th(256);

  if (ws_size >= (size_t)268435456){
    // -------- full-batch path, 256 MiB --------
    // [0, 8M)      : F spectrum [ky][kx] -- last read by k_fft_inv_filter_t,
    //                then reused as median scratch.
    // [8M, 248M)   : Z, 30 planes of 8 MB
    // [248M, 252M) : lnr table   [252M, 256M) : theta table
    c2* F  = (c2*)(w);
    c2* Z  = (c2*)(w + 8388608);
    float* lnrT   = (float*)(w + 260046848);
    float* thetaT = (float*)(w + 264241152);
    unsigned* g1  = (unsigned*)(w);
    unsigned* g2  = (unsigned*)(w + 98304);
    unsigned* g3  = (unsigned*)(w + 294912);
    unsigned* sc1 = (unsigned*)(w + 307200);
    unsigned* sc2 = (unsigned*)(w + 307328);
    float* Tval   = (float*)(w + 307456);

    k_filt_tab<<<dim3(1024), th, 0, stream>>>(lnrT, thetaT);

    // forward: rowFFT(img) -> F[y][kx] ; col slab FFT over y -> F[ky][kx]
    k_fft_fwd_real<<<dim3(256), th, 0, stream>>>(img, F);
    k_fft_col_slab<-1><<<dim3(128, 1), th, 0, stream>>>(F);

    // 30 channels: filter ⊙ + row IFFT over kx -> Z[ky][x]; col slab IFFT over ky -> z[y][x]
    k_fft_inv_filter_t<<<dim3(256, 30), th, 0, stream>>>(F, Z, lnrT, thetaT);
    k_fft_col_slab<1><<<dim3(128, 30), th, 0, stream>>>(Z);

    // medians for 6 orientations (scale-0 planes), batched
    hipMemsetAsync(g1, 0, 6*16384, stream);
    const size_t oStride = (size_t)5 * 1048576;
    k_med_p1b<<<dim3(64, 6), th, 0, stream>>>(Z, oStride, g1, 0);
    k_sel1b<<<dim3(6), th, 0, stream>>>(g1, sc1, g2, 0);
    k_med_p2b<<<dim3(64, 6), th, 0, stream>>>(Z, oStride, sc1, g2, 0);
    k_sel2b<<<dim3(6), th, 0, stream>>>(g2, sc1, sc2, g3, 0);
    k_med_p3b<<<dim3(64, 6), th, 0, stream>>>(Z, oStride, sc1, sc2, g3, 0);
    k_sel3b<<<dim3(6), th, 0, stream>>>(g3, sc1, sc2, Tval, 0);

    // fused per-pixel PC + covariance + M,m (planes in natural layout)
    k_pix_all<<<dim3(4096), th, 0, stream>>>(Z, Tval, out);
  } else {
    // -------- fallback: per-orientation (needs ~63 MB) --------
    c2* F   = (c2*)(w);
    c2* C5  = (c2*)(w + 8388608);                 // 5 planes, 40 MB
    float* ax2 = (float*)(w + 50331648);
    float* ay2 = ax2 + 1048576;
    float* axy = ay2 + 1048576;
    unsigned* g1  = (unsigned*)(w + 62914560);
    unsigned* g2  = (unsigned*)(w + 62930944);
    unsigned* g3  = (unsigned*)(w + 62963712);
    unsigned* sc1 = (unsigned*)(w + 62965760);
    unsigned* sc2 = (unsigned*)(w + 62965888);
    float* Tval   = (float*)(w + 62966016);

    k_fft_fwd_real<<<dim3(256), th, 0, stream>>>(img, F);
    k_fft_col_slab<-1><<<dim3(128, 1), th, 0, stream>>>(F);

    for (int o = 0; o < 6; ++o){
      k_fft_inv_filter_b<<<dim3(256, 5), th, 0, stream>>>(F, C5, o*5);
      k_fft_col_slab<1><<<dim3(128, 5), th, 0, stream>>>(C5);

      hipMemsetAsync(g1, 0, 16384, stream);
      k_med_p1b<<<dim3(64, 1), th, 0, stream>>>(C5, 0, g1, 0);
      k_sel1b<<<dim3(1), th, 0, stream>>>(g1, sc1, g2, 0);
      k_med_p2b<<<dim3(64, 1), th, 0, stream>>>(C5, 0, sc1, g2, 0);
      k_sel2b<<<dim3(1), th, 0, stream>>>(g2, sc1, sc2, g3, 0);
      k_med_p3b<<<dim3(64, 1), th, 0, stream>>>(C5, 0, sc1, sc2, g3, 0);
      k_sel3b<<<dim3(1), th, 0, stream>>>(g3, sc1, sc2, Tval, 0);

      const double a = (double)o * (M_PI/6.0);
      k_pix<<<dim3(4096), th, 0, stream>>>(C5, Tval, (float)cos(a), (float)sin(a),
                                           ax2, ay2, axy, (o == 0) ? 1 : 0);
    }
    k_final<<<dim3(4096), th, 0, stream>>>(ax2, ay2, axy, out);
  }
}